// Round 1
// baseline (2885.842 us; speedup 1.0000x reference)
//
#include <hip/hip_runtime.h>
#include <hip/hip_bf16.h>

#define NFEAT  128
#define HC     64
#define HEADS  4
#define NHID   16
#define NCLASS 40
#define NEG    0.2f
#define BN_EPS 1e-5f

__device__ __forceinline__ void fatomic_add(float* p, float v) {
    unsafeAtomicAdd(p, v);   // global_atomic_add_f32 on gfx950
}

// ---------------------------------------------------------------------------
// Kernel 1: h1 = x @ W1  (W1 staged in LDS), per-head scores a_s, a_d.
// One wave per row; lane = output channel (0..63). x row staged in per-wave LDS.
// ---------------------------------------------------------------------------
__global__ __launch_bounds__(256) void k_gemm1(
    const float* __restrict__ x, const float* __restrict__ W1,
    const float* __restrict__ att_s, const float* __restrict__ att_d,
    float* __restrict__ h1, float* __restrict__ as1, float* __restrict__ ad1,
    int n)
{
    __shared__ float sW[NFEAT * HC];     // 32 KB
    __shared__ float sx[4][NFEAT];       // 2 KB, per-wave row buffer
    for (int i = threadIdx.x; i < NFEAT * HC; i += 256) sW[i] = W1[i];
    __syncthreads();

    const int wave = threadIdx.x >> 6, lane = threadIdx.x & 63;
    const float av = att_s[lane];        // att_src1 flat [4][16] == channel idx
    const float bv = att_d[lane];
    const int stride = gridDim.x * 4;

    for (int row = blockIdx.x * 4 + wave; row < n; row += stride) {
        sx[wave][lane]      = x[(size_t)row * NFEAT + lane];
        sx[wave][lane + 64] = x[(size_t)row * NFEAT + lane + 64];
        __threadfence_block();           // wave-synchronous LDS: order write->read

        float acc = 0.f;
        #pragma unroll
        for (int k = 0; k < NFEAT; ++k)
            acc = fmaf(sx[wave][k], sW[k * HC + lane], acc);

        h1[(size_t)row * HC + lane] = acc;

        float s = acc * av, d = acc * bv;
        #pragma unroll
        for (int off = 8; off >= 1; off >>= 1) {
            s += __shfl_xor(s, off, 64);
            d += __shfl_xor(d, off, 64);
        }
        if ((lane & 15) == 0) {
            as1[row * HEADS + (lane >> 4)] = s;
            ad1[row * HEADS + (lane >> 4)] = d;
        }
        __threadfence_block();           // reads of sx done before next-iter write
    }
}

// ---------------------------------------------------------------------------
// Kernel 2: edge pass layer 1. 16 lanes per edge; lane sub handles channels
// 4*sub..4*sub+3 (float4). Unnormalized softmax: denom + ex*h1[src] scatter.
// ---------------------------------------------------------------------------
__global__ __launch_bounds__(256) void k_edge1(
    const int* __restrict__ esrc, const int* __restrict__ edst,
    const float* __restrict__ h1, const float* __restrict__ as1,
    const float* __restrict__ ad1,
    float* __restrict__ den1, float* __restrict__ out1, int E, int n)
{
    const int gid = blockIdx.x * 256 + threadIdx.x;
    const int e   = gid >> 4;
    const int Et  = E + n;
    if (e >= Et) return;
    const int sub = threadIdx.x & 15;

    int s, d;
    if (e < E) { s = esrc[e]; d = edst[e]; }
    else       { s = d = e - E; }        // self-loop

    float ex = 0.f;
    if (sub < HEADS) {
        float a = as1[s * HEADS + sub] + ad1[d * HEADS + sub];
        a = (a > 0.f) ? a : NEG * a;
        ex = __expf(a);
        fatomic_add(den1 + d * HEADS + sub, ex);
    }
    const int lane = threadIdx.x & 63;
    // channel group 4*sub..4*sub+3 lies in head sub>>2; fetch its ex
    const float exh = __shfl(ex, (lane & ~15) + (sub >> 2), 64);

    const float4 hv = *(const float4*)(h1 + (size_t)s * HC + sub * 4);
    float* op = out1 + (size_t)d * HC + sub * 4;
    fatomic_add(op + 0, exh * hv.x);
    fatomic_add(op + 1, exh * hv.y);
    fatomic_add(op + 2, exh * hv.z);
    fatomic_add(op + 3, exh * hv.w);
}

// ---------------------------------------------------------------------------
// Kernel 3: per node — normalize layer1, +bias1, BN, ReLU, g = h @ W2,
// layer-2 scores; also zero den2. One wave per node, W2 in LDS.
// ---------------------------------------------------------------------------
__global__ __launch_bounds__(256) void k_mid(
    const float* __restrict__ out1, const float* __restrict__ den1,
    const float* __restrict__ bias1, const float* __restrict__ gamma,
    const float* __restrict__ beta, const float* __restrict__ mean,
    const float* __restrict__ var,
    const float* __restrict__ W2, const float* __restrict__ ats2,
    const float* __restrict__ atd2,
    float* __restrict__ g, float* __restrict__ as2, float* __restrict__ ad2,
    float* __restrict__ den2, int n)
{
    __shared__ float sW[HC * NCLASS];    // 10 KB
    __shared__ float sh[4][HC];
    for (int i = threadIdx.x; i < HC * NCLASS; i += 256) sW[i] = W2[i];
    __syncthreads();

    const int wave = threadIdx.x >> 6, lane = threadIdx.x & 63;
    const float b1    = bias1[lane];
    const float scale = gamma[lane] * rsqrtf(var[lane] + BN_EPS);
    const float shift = beta[lane] - mean[lane] * scale;
    const float a2 = (lane < NCLASS) ? ats2[lane] : 0.f;
    const float d2 = (lane < NCLASS) ? atd2[lane] : 0.f;
    const int stride = gridDim.x * 4;

    for (int node = blockIdx.x * 4 + wave; node < n; node += stride) {
        float v = out1[(size_t)node * HC + lane] / den1[node * HEADS + (lane >> 4)] + b1;
        v = fmaf(v, scale, shift);
        v = fmaxf(v, 0.f);
        sh[wave][lane] = v;
        __threadfence_block();

        float gv = 0.f;
        if (lane < NCLASS) {
            #pragma unroll
            for (int k = 0; k < HC; ++k)
                gv = fmaf(sh[wave][k], sW[k * NCLASS + lane], gv);
            g[(size_t)node * NCLASS + lane] = gv;
        }
        float sv = gv * a2, dv = gv * d2;
        #pragma unroll
        for (int off = 32; off >= 1; off >>= 1) {
            sv += __shfl_xor(sv, off, 64);
            dv += __shfl_xor(dv, off, 64);
        }
        if (lane == 0) { as2[node] = sv; ad2[node] = dv; den2[node] = 0.f; }
        __threadfence_block();
    }
}

// ---------------------------------------------------------------------------
// Kernel 4: edge pass layer 2 (1 head, 40 channels). Accumulates into d_out.
// ---------------------------------------------------------------------------
__global__ __launch_bounds__(256) void k_edge2(
    const int* __restrict__ esrc, const int* __restrict__ edst,
    const float* __restrict__ g, const float* __restrict__ as2,
    const float* __restrict__ ad2,
    float* __restrict__ den2, float* __restrict__ out, int E, int n)
{
    const int gid = blockIdx.x * 256 + threadIdx.x;
    const int e   = gid >> 4;
    const int Et  = E + n;
    if (e >= Et) return;
    const int sub = threadIdx.x & 15;

    int s, d;
    if (e < E) { s = esrc[e]; d = edst[e]; }
    else       { s = d = e - E; }

    float ex = 0.f;
    if (sub == 0) {
        float a = as2[s] + ad2[d];
        a = (a > 0.f) ? a : NEG * a;
        ex = __expf(a);
        fatomic_add(den2 + d, ex);
    }
    const int lane = threadIdx.x & 63;
    const float exh = __shfl(ex, lane & ~15, 64);

    if (sub < 10) {                      // 10 * float4 = 40 channels
        const float4 gv = *(const float4*)(g + (size_t)s * NCLASS + sub * 4);
        float* op = out + (size_t)d * NCLASS + sub * 4;
        fatomic_add(op + 0, exh * gv.x);
        fatomic_add(op + 1, exh * gv.y);
        fatomic_add(op + 2, exh * gv.z);
        fatomic_add(op + 3, exh * gv.w);
    }
}

// ---------------------------------------------------------------------------
// Kernel 5: out = out / den2 + bias2
// ---------------------------------------------------------------------------
__global__ __launch_bounds__(256) void k_final(
    float* __restrict__ out, const float* __restrict__ den2,
    const float* __restrict__ bias2, int n)
{
    const int idx = blockIdx.x * 256 + threadIdx.x;
    if (idx >= n * NCLASS) return;
    const int node = idx / NCLASS;
    const int c    = idx - node * NCLASS;
    out[idx] = out[idx] / den2[node] + bias2[c];
}

extern "C" void kernel_launch(void* const* d_in, const int* in_sizes, int n_in,
                              void* d_out, int out_size, void* d_ws, size_t ws_size,
                              hipStream_t stream)
{
    const float* x    = (const float*)d_in[0];
    const int*   ei   = (const int*)  d_in[1];   // [2,E] int32
    const float* W1   = (const float*)d_in[2];
    const float* as1w = (const float*)d_in[3];
    const float* ad1w = (const float*)d_in[4];
    const float* b1   = (const float*)d_in[5];
    const float* gm   = (const float*)d_in[6];
    const float* bt   = (const float*)d_in[7];
    const float* mn   = (const float*)d_in[8];
    const float* vr   = (const float*)d_in[9];
    const float* W2   = (const float*)d_in[10];
    const float* as2w = (const float*)d_in[11];
    const float* ad2w = (const float*)d_in[12];
    const float* b2   = (const float*)d_in[13];

    const int n = in_sizes[0] / NFEAT;           // 100000
    const int E = in_sizes[1] / 2;               // 1600000
    const int* esrc = ei;
    const int* edst = ei + E;

    // workspace layout (floats): h1(64n) | a_s1(4n) | a_d1(4n) | den1(4n) | out1(64n)
    // reuse: g -> h1 region (h1 dead after edge1); as2/ad2/den2 -> a_s1 region
    float* ws   = (float*)d_ws;
    float* h1   = ws;
    float* a_s1 = ws   + (size_t)n * 64;
    float* a_d1 = a_s1 + (size_t)n * 4;
    float* den1 = a_d1 + (size_t)n * 4;
    float* out1 = den1 + (size_t)n * 4;
    float* gbuf = h1;            // reuse
    float* a_s2 = a_s1;          // reuse
    float* a_d2 = a_s1 + n;
    float* den2 = a_s1 + 2 * (size_t)n;
    float* outv = (float*)d_out;

    // zero accumulators (den1 and out1 are contiguous: 68n floats)
    hipMemsetAsync(den1, 0, (size_t)n * 68 * sizeof(float), stream);
    hipMemsetAsync(d_out, 0, (size_t)n * NCLASS * sizeof(float), stream);

    const int Et = E + n;
    const int eb = (Et * 16 + 255) / 256;

    k_gemm1<<<2048, 256, 0, stream>>>(x, W1, as1w, ad1w, h1, a_s1, a_d1, n);
    k_edge1<<<eb, 256, 0, stream>>>(esrc, edst, h1, a_s1, a_d1, den1, out1, E, n);
    k_mid<<<2048, 256, 0, stream>>>(out1, den1, b1, gm, bt, mn, vr, W2, as2w, ad2w,
                                    gbuf, a_s2, a_d2, den2, n);
    k_edge2<<<eb, 256, 0, stream>>>(esrc, edst, gbuf, a_s2, a_d2, den2, outv, E, n);
    k_final<<<(n * NCLASS + 255) / 256, 256, 0, stream>>>(outv, den2, b2, n);
}

// Round 2
// 793.991 us; speedup vs baseline: 3.6346x; 3.6346x over previous
//
#include <hip/hip_runtime.h>
#include <hip/hip_bf16.h>

#define NFEAT  128
#define HC     64
#define HEADS  4
#define NHID   16
#define NCLASS 40
#define NEG    0.2f
#define BN_EPS 1e-5f

// ---------------------------------------------------------------------------
// Kernel 1: h1 = x @ W1  (W1 staged in LDS), one wave per row, lane = channel.
// ---------------------------------------------------------------------------
__global__ __launch_bounds__(256) void k_gemm1(
    const float* __restrict__ x, const float* __restrict__ W1,
    const float* __restrict__ att_s, const float* __restrict__ att_d,
    float* __restrict__ h1, float* __restrict__ as1, float* __restrict__ ad1,
    int n)
{
    __shared__ float sW[NFEAT * HC];     // 32 KB
    __shared__ float sx[4][NFEAT];       // 2 KB, per-wave row buffer
    for (int i = threadIdx.x; i < NFEAT * HC; i += 256) sW[i] = W1[i];
    __syncthreads();

    const int wave = threadIdx.x >> 6, lane = threadIdx.x & 63;
    const float av = att_s[lane];        // att_src1 flat [4][16] == channel idx
    const float bv = att_d[lane];
    const int stride = gridDim.x * 4;

    for (int row = blockIdx.x * 4 + wave; row < n; row += stride) {
        sx[wave][lane]      = x[(size_t)row * NFEAT + lane];
        sx[wave][lane + 64] = x[(size_t)row * NFEAT + lane + 64];
        __threadfence_block();

        float acc = 0.f;
        #pragma unroll
        for (int k = 0; k < NFEAT; ++k)
            acc = fmaf(sx[wave][k], sW[k * HC + lane], acc);

        h1[(size_t)row * HC + lane] = acc;

        float s = acc * av, d = acc * bv;
        #pragma unroll
        for (int off = 8; off >= 1; off >>= 1) {
            s += __shfl_xor(s, off, 64);
            d += __shfl_xor(d, off, 64);
        }
        if ((lane & 15) == 0) {
            as1[row * HEADS + (lane >> 4)] = s;
            ad1[row * HEADS + (lane >> 4)] = d;
        }
        __threadfence_block();
    }
}

// ---------------------------------------------------------------------------
// CSR build: degree count -> exclusive scan -> fill
// ---------------------------------------------------------------------------
__global__ __launch_bounds__(256) void k_count(
    const int* __restrict__ edst, int* __restrict__ deg, int E)
{
    int i = blockIdx.x * 256 + threadIdx.x;
    if (i < E) atomicAdd(deg + edst[i], 1);
}

// single workgroup, 1024 threads; exclusive scan deg[0..n) -> rowptr[0..n]
__global__ __launch_bounds__(1024) void k_scan(
    const int* __restrict__ deg, int* __restrict__ rowptr, int n)
{
    __shared__ int wsum[16];
    const int tid = threadIdx.x, lane = tid & 63, w = tid >> 6;
    int carry = 0;
    for (int base = 0; base < n; base += 1024) {
        const int idx = base + tid;
        int v = (idx < n) ? deg[idx] : 0;
        int sc = v;
        #pragma unroll
        for (int off = 1; off < 64; off <<= 1) {
            int t = __shfl_up(sc, off, 64);
            if (lane >= off) sc += t;
        }
        if (lane == 63) wsum[w] = sc;
        __syncthreads();
        if (w == 0 && lane < 16) {
            int s = wsum[lane];
            #pragma unroll
            for (int off = 1; off < 16; off <<= 1) {
                int t = __shfl_up(s, off, 16);
                if (lane >= off) s += t;
            }
            wsum[lane] = s;
        }
        __syncthreads();
        const int woff = (w > 0) ? wsum[w - 1] : 0;
        if (idx < n) rowptr[idx + 1] = carry + woff + sc;
        carry += wsum[15];
        __syncthreads();
    }
    if (tid == 0) rowptr[0] = 0;
}

__global__ __launch_bounds__(256) void k_fill(
    const int* __restrict__ esrc, const int* __restrict__ edst,
    const int* __restrict__ rowptr, int* __restrict__ cursor,
    int* __restrict__ csr, int E)
{
    int i = blockIdx.x * 256 + threadIdx.x;
    if (i >= E) return;
    const int d = edst[i];
    const int pos = atomicAdd(cursor + d, 1);
    csr[rowptr[d] + pos] = esrc[i];
}

// ---------------------------------------------------------------------------
// Kernel agg1: one wave per node. Gather-accumulate layer-1 softmax+aggregation
// (no atomics), then fused normalize + bias1 + BN + ReLU + GEMM2 + L2 scores.
// ---------------------------------------------------------------------------
__global__ __launch_bounds__(256) void k_agg1(
    const int* __restrict__ csr, const int* __restrict__ rowptr,
    const float* __restrict__ h1, const float* __restrict__ as1,
    const float* __restrict__ ad1,
    const float* __restrict__ bias1, const float* __restrict__ gamma,
    const float* __restrict__ beta, const float* __restrict__ mean,
    const float* __restrict__ var,
    const float* __restrict__ W2, const float* __restrict__ ats2,
    const float* __restrict__ atd2,
    float* __restrict__ g, float* __restrict__ as2o, float* __restrict__ ad2o,
    int n)
{
    __shared__ float sW[HC * NCLASS];    // 10 KB
    __shared__ float sh[4][HC];
    for (int i = threadIdx.x; i < HC * NCLASS; i += 256) sW[i] = W2[i];
    __syncthreads();

    const int wave = threadIdx.x >> 6, lane = threadIdx.x & 63;
    const int h = lane >> 4;
    const float b1    = bias1[lane];
    const float scale = gamma[lane] * rsqrtf(var[lane] + BN_EPS);
    const float shift = beta[lane] - mean[lane] * scale;
    const float a2 = (lane < NCLASS) ? ats2[lane] : 0.f;
    const float d2 = (lane < NCLASS) ? atd2[lane] : 0.f;

    for (int node = blockIdx.x * 4 + wave; node < n; node += gridDim.x * 4) {
        const float ad1d = ad1[node * HEADS + h];
        // self-loop (appended by reference)
        float a = as1[node * HEADS + h] + ad1d;
        a = (a > 0.f) ? a : NEG * a;
        float ex  = __expf(a);
        float den = ex;
        float acc = ex * h1[(size_t)node * HC + lane];

        const int row = rowptr[node], end = rowptr[node + 1];
        for (int base = row; base < end; base += 64) {
            const int eid = (base + lane < end) ? csr[base + lane] : 0;
            const int m = min(64, end - base);
            for (int i = 0; i < m; ++i) {
                const int s = __shfl(eid, i, 64);
                float aa = as1[s * HEADS + h] + ad1d;
                aa = (aa > 0.f) ? aa : NEG * aa;
                const float e = __expf(aa);
                acc = fmaf(e, h1[(size_t)s * HC + lane], acc);
                den += e;
            }
        }

        float v = acc / den + b1;
        v = fmaf(v, scale, shift);
        v = fmaxf(v, 0.f);
        sh[wave][lane] = v;
        __threadfence_block();

        float gv = 0.f;
        if (lane < NCLASS) {
            #pragma unroll
            for (int k = 0; k < HC; ++k)
                gv = fmaf(sh[wave][k], sW[k * NCLASS + lane], gv);
            g[(size_t)node * NCLASS + lane] = gv;
        }
        float sv = gv * a2, dv = gv * d2;
        #pragma unroll
        for (int off = 32; off >= 1; off >>= 1) {
            sv += __shfl_xor(sv, off, 64);
            dv += __shfl_xor(dv, off, 64);
        }
        if (lane == 0) { as2o[node] = sv; ad2o[node] = dv; }
        __threadfence_block();
    }
}

// ---------------------------------------------------------------------------
// Kernel agg2: one wave per node, layer-2 aggregation + final bias. No atomics.
// ---------------------------------------------------------------------------
__global__ __launch_bounds__(256) void k_agg2(
    const int* __restrict__ csr, const int* __restrict__ rowptr,
    const float* __restrict__ g, const float* __restrict__ as2,
    const float* __restrict__ ad2, const float* __restrict__ bias2,
    float* __restrict__ out, int n)
{
    const int wave = threadIdx.x >> 6, lane = threadIdx.x & 63;
    const float b2 = (lane < NCLASS) ? bias2[lane] : 0.f;

    for (int node = blockIdx.x * 4 + wave; node < n; node += gridDim.x * 4) {
        const float ad2d = ad2[node];
        float a = as2[node] + ad2d;
        a = (a > 0.f) ? a : NEG * a;
        float ex  = __expf(a);
        float den = ex;
        float acc = (lane < NCLASS) ? ex * g[(size_t)node * NCLASS + lane] : 0.f;

        const int row = rowptr[node], end = rowptr[node + 1];
        for (int base = row; base < end; base += 64) {
            const int eid = (base + lane < end) ? csr[base + lane] : 0;
            const int m = min(64, end - base);
            for (int i = 0; i < m; ++i) {
                const int s = __shfl(eid, i, 64);
                float aa = as2[s] + ad2d;
                aa = (aa > 0.f) ? aa : NEG * aa;
                const float e = __expf(aa);
                if (lane < NCLASS)
                    acc = fmaf(e, g[(size_t)s * NCLASS + lane], acc);
                den += e;
            }
        }
        if (lane < NCLASS)
            out[(size_t)node * NCLASS + lane] = acc / den + b2;
    }
}

extern "C" void kernel_launch(void* const* d_in, const int* in_sizes, int n_in,
                              void* d_out, int out_size, void* d_ws, size_t ws_size,
                              hipStream_t stream)
{
    const float* x    = (const float*)d_in[0];
    const int*   ei   = (const int*)  d_in[1];   // [2,E] int32
    const float* W1   = (const float*)d_in[2];
    const float* as1w = (const float*)d_in[3];
    const float* ad1w = (const float*)d_in[4];
    const float* b1   = (const float*)d_in[5];
    const float* gm   = (const float*)d_in[6];
    const float* bt   = (const float*)d_in[7];
    const float* mn   = (const float*)d_in[8];
    const float* vr   = (const float*)d_in[9];
    const float* W2   = (const float*)d_in[10];
    const float* as2w = (const float*)d_in[11];
    const float* ad2w = (const float*)d_in[12];
    const float* b2   = (const float*)d_in[13];

    const int n = in_sizes[0] / NFEAT;           // 100000
    const int E = in_sizes[1] / 2;               // 1600000
    const int* esrc = ei;
    const int* edst = ei + E;

    // workspace layout (4-byte units):
    // h1(64n) | as1(4n) | ad1(4n) | g(40n) | as2(n) | ad2(n) |
    // deg(n) cursor(n) [contiguous -> one memset] | rowptr(n+1) | csr(E)
    float* ws   = (float*)d_ws;
    float* h1   = ws;
    float* a_s1 = h1   + (size_t)n * 64;
    float* a_d1 = a_s1 + (size_t)n * 4;
    float* gbuf = a_d1 + (size_t)n * 4;
    float* a_s2 = gbuf + (size_t)n * NCLASS;
    float* a_d2 = a_s2 + n;
    int*   deg    = (int*)(a_d2 + n);
    int*   cursor = deg + n;
    int*   rowptr = cursor + n;
    int*   csr    = rowptr + (n + 1);
    float* outv = (float*)d_out;

    hipMemsetAsync(deg, 0, (size_t)n * 2 * sizeof(int), stream);  // deg + cursor

    const int eb = (E + 255) / 256;
    const int nb = (n + 3) / 4;

    k_count<<<eb, 256, 0, stream>>>(edst, deg, E);
    k_scan <<<1, 1024, 0, stream>>>(deg, rowptr, n);
    k_fill <<<eb, 256, 0, stream>>>(esrc, edst, rowptr, cursor, csr, E);
    k_gemm1<<<2048, 256, 0, stream>>>(x, W1, as1w, ad1w, h1, a_s1, a_d1, n);
    k_agg1 <<<nb, 256, 0, stream>>>(csr, rowptr, h1, a_s1, a_d1, b1, gm, bt, mn, vr,
                                    W2, as2w, ad2w, gbuf, a_s2, a_d2, n);
    k_agg2 <<<nb, 256, 0, stream>>>(csr, rowptr, gbuf, a_s2, a_d2, b2, outv, n);
}

// Round 3
// 555.136 us; speedup vs baseline: 5.1984x; 1.4303x over previous
//
#include <hip/hip_runtime.h>
#include <hip/hip_bf16.h>

#define NFEAT  128
#define HC     64
#define HEADS  4
#define NHID   16
#define NCLASS 40
#define NEG    0.2f
#define BN_EPS 1e-5f

__device__ __forceinline__ float leaky(float a) { return (a > 0.f) ? a : NEG * a; }

// ---------------------------------------------------------------------------
// Kernel 1: h1 = x @ W1  (W1 staged in LDS), one wave per row, lane = channel.
// ---------------------------------------------------------------------------
__global__ __launch_bounds__(256) void k_gemm1(
    const float* __restrict__ x, const float* __restrict__ W1,
    const float* __restrict__ att_s, const float* __restrict__ att_d,
    float* __restrict__ h1, float* __restrict__ as1, float* __restrict__ ad1,
    int n)
{
    __shared__ float sW[NFEAT * HC];     // 32 KB
    __shared__ float sx[4][NFEAT];       // 2 KB, per-wave row buffer
    for (int i = threadIdx.x; i < NFEAT * HC; i += 256) sW[i] = W1[i];
    __syncthreads();

    const int wave = threadIdx.x >> 6, lane = threadIdx.x & 63;
    const float av = att_s[lane];        // att_src1 flat [4][16] == channel idx
    const float bv = att_d[lane];
    const int stride = gridDim.x * 4;

    for (int row = blockIdx.x * 4 + wave; row < n; row += stride) {
        sx[wave][lane]      = x[(size_t)row * NFEAT + lane];
        sx[wave][lane + 64] = x[(size_t)row * NFEAT + lane + 64];
        __threadfence_block();

        float acc = 0.f;
        #pragma unroll
        for (int k4 = 0; k4 < NFEAT; k4 += 4) {
            const float4 xv = *(const float4*)&sx[wave][k4];
            acc = fmaf(xv.x, sW[(k4 + 0) * HC + lane], acc);
            acc = fmaf(xv.y, sW[(k4 + 1) * HC + lane], acc);
            acc = fmaf(xv.z, sW[(k4 + 2) * HC + lane], acc);
            acc = fmaf(xv.w, sW[(k4 + 3) * HC + lane], acc);
        }

        h1[(size_t)row * HC + lane] = acc;

        float s = acc * av, d = acc * bv;
        #pragma unroll
        for (int off = 8; off >= 1; off >>= 1) {
            s += __shfl_xor(s, off, 64);
            d += __shfl_xor(d, off, 64);
        }
        if ((lane & 15) == 0) {
            as1[row * HEADS + (lane >> 4)] = s;
            ad1[row * HEADS + (lane >> 4)] = d;
        }
        __threadfence_block();
    }
}

// ---------------------------------------------------------------------------
// CSR build: degree count -> 3-kernel scan -> fill
// ---------------------------------------------------------------------------
__global__ __launch_bounds__(256) void k_count(
    const int* __restrict__ edst, int* __restrict__ deg, int E)
{
    int i = blockIdx.x * 256 + threadIdx.x;
    if (i < E) atomicAdd(deg + edst[i], 1);
}

// per-block inclusive scan of 1024 deg entries -> rowptr[idx+1] (local), bsum[b]
__global__ __launch_bounds__(1024) void k_scan1(
    const int* __restrict__ deg, int* __restrict__ rowptr,
    int* __restrict__ bsum, int n)
{
    __shared__ int wsum[16];
    const int tid = threadIdx.x, lane = tid & 63, w = tid >> 6;
    const int idx = blockIdx.x * 1024 + tid;
    int v = (idx < n) ? deg[idx] : 0;
    int sc = v;
    #pragma unroll
    for (int off = 1; off < 64; off <<= 1) {
        int t = __shfl_up(sc, off, 64);
        if (lane >= off) sc += t;
    }
    if (lane == 63) wsum[w] = sc;
    __syncthreads();
    if (w == 0 && lane < 16) {
        int s = wsum[lane];
        #pragma unroll
        for (int off = 1; off < 16; off <<= 1) {
            int t = __shfl_up(s, off, 16);
            if (lane >= off) s += t;
        }
        wsum[lane] = s;
    }
    __syncthreads();
    const int woff = (w > 0) ? wsum[w - 1] : 0;
    if (idx < n) rowptr[idx + 1] = woff + sc;
    if (tid == 0) bsum[blockIdx.x] = wsum[15];
}

// single block (128 thr): exclusive scan of nb block sums, in place
__global__ __launch_bounds__(128) void k_scan2(int* __restrict__ bsum, int nb)
{
    __shared__ int ws2[2];
    const int tid = threadIdx.x, lane = tid & 63, w = tid >> 6;
    int v = (tid < nb) ? bsum[tid] : 0;
    int sc = v;
    #pragma unroll
    for (int off = 1; off < 64; off <<= 1) {
        int t = __shfl_up(sc, off, 64);
        if (lane >= off) sc += t;
    }
    if (lane == 63) ws2[w] = sc;
    __syncthreads();
    const int incl = sc + ((w == 1) ? ws2[0] : 0);
    if (tid < nb) bsum[tid] = incl - v;     // exclusive
}

// add block offsets; set rowptr[0]
__global__ __launch_bounds__(256) void k_scan3(
    int* __restrict__ rowptr, const int* __restrict__ bsum, int n)
{
    const int idx = blockIdx.x * 256 + threadIdx.x;
    if (idx < n) rowptr[idx + 1] += bsum[idx >> 10];
    if (idx == 0) rowptr[0] = 0;
}

__global__ __launch_bounds__(256) void k_fill(
    const int* __restrict__ esrc, const int* __restrict__ edst,
    const int* __restrict__ rowptr, int* __restrict__ cursor,
    int* __restrict__ csr, int E)
{
    int i = blockIdx.x * 256 + threadIdx.x;
    if (i >= E) return;
    const int d = edst[i];
    const int pos = atomicAdd(cursor + d, 1);
    csr[rowptr[d] + pos] = esrc[i];
}

// ---------------------------------------------------------------------------
// Kernel agg1: one wave per node. Parallel score-prefetch phase (per-lane edge)
// -> LDS, denominator via butterfly; inner loop is pure gather+fmaf, unroll 4.
// Fused: normalize + bias1 + BN + ReLU + GEMM2 + layer-2 scores.
// ---------------------------------------------------------------------------
__global__ __launch_bounds__(256) void k_agg1(
    const int* __restrict__ csr, const int* __restrict__ rowptr,
    const float* __restrict__ h1, const float* __restrict__ as1,
    const float* __restrict__ ad1,
    const float* __restrict__ bias1, const float* __restrict__ gamma,
    const float* __restrict__ beta, const float* __restrict__ mean,
    const float* __restrict__ var,
    const float* __restrict__ W2, const float* __restrict__ ats2,
    const float* __restrict__ atd2,
    float* __restrict__ g, float* __restrict__ as2o, float* __restrict__ ad2o,
    int n)
{
    __shared__ float sW[HC * NCLASS];    // 10 KB
    __shared__ float sh[4][HC];
    __shared__ float sE[4][64 * 4];      // e per edge per head (4 KB)
    __shared__ int   sS[4][64];
    for (int i = threadIdx.x; i < HC * NCLASS; i += 256) sW[i] = W2[i];
    __syncthreads();

    const int wave = threadIdx.x >> 6, lane = threadIdx.x & 63;
    const int h = lane >> 4;
    const float b1    = bias1[lane];
    const float scale = gamma[lane] * rsqrtf(var[lane] + BN_EPS);
    const float shift = beta[lane] - mean[lane] * scale;
    const float a2 = (lane < NCLASS) ? ats2[lane] : 0.f;
    const float d2 = (lane < NCLASS) ? atd2[lane] : 0.f;

    for (int node = blockIdx.x * 4 + wave; node < n; node += gridDim.x * 4) {
        const float4 adv = *(const float4*)(ad1 + node * HEADS);
        const float4 sv4 = *(const float4*)(as1 + node * HEADS);
        // self-loop exp, all 4 heads (uniform across lanes)
        float4 eself;
        eself.x = __expf(leaky(sv4.x + adv.x));
        eself.y = __expf(leaky(sv4.y + adv.y));
        eself.z = __expf(leaky(sv4.z + adv.z));
        eself.w = __expf(leaky(sv4.w + adv.w));
        const float esel = (h == 0) ? eself.x : (h == 1) ? eself.y
                         : (h == 2) ? eself.z : eself.w;

        float acc0 = esel * h1[(size_t)node * HC + lane];
        float acc1 = 0.f;
        float4 dpart = {0.f, 0.f, 0.f, 0.f};   // per-lane partial denominators

        const int row = rowptr[node], end = rowptr[node + 1];
        for (int base = row; base < end; base += 64) {
            const int m = min(64, end - base);
            float4 e4 = {0.f, 0.f, 0.f, 0.f};
            int eid = 0;
            if (lane < m) {
                eid = csr[base + lane];
                const float4 s4 = *(const float4*)(as1 + eid * HEADS);
                e4.x = __expf(leaky(s4.x + adv.x));
                e4.y = __expf(leaky(s4.y + adv.y));
                e4.z = __expf(leaky(s4.z + adv.z));
                e4.w = __expf(leaky(s4.w + adv.w));
            }
            dpart.x += e4.x; dpart.y += e4.y; dpart.z += e4.z; dpart.w += e4.w;
            *(float4*)&sE[wave][lane * 4] = e4;
            sS[wave][lane] = eid;
            __threadfence_block();

            const float* eB = &sE[wave][0];
            const int*   sB = &sS[wave][0];
            int i = 0;
            for (; i + 4 <= m; i += 4) {
                const int s0 = sB[i + 0], s1 = sB[i + 1];
                const int s2 = sB[i + 2], s3 = sB[i + 3];
                const float e0 = eB[(i + 0) * 4 + h], e1 = eB[(i + 1) * 4 + h];
                const float e2 = eB[(i + 2) * 4 + h], e3 = eB[(i + 3) * 4 + h];
                const float v0 = h1[(size_t)s0 * HC + lane];
                const float v1 = h1[(size_t)s1 * HC + lane];
                const float v2 = h1[(size_t)s2 * HC + lane];
                const float v3 = h1[(size_t)s3 * HC + lane];
                acc0 = fmaf(e0, v0, acc0);
                acc1 = fmaf(e1, v1, acc1);
                acc0 = fmaf(e2, v2, acc0);
                acc1 = fmaf(e3, v3, acc1);
            }
            for (; i < m; ++i)
                acc0 = fmaf(eB[i * 4 + h], h1[(size_t)sB[i] * HC + lane], acc0);
            __threadfence_block();
        }

        // reduce denominators across lanes, add self-loop once
        #pragma unroll
        for (int off = 32; off >= 1; off >>= 1) {
            dpart.x += __shfl_xor(dpart.x, off, 64);
            dpart.y += __shfl_xor(dpart.y, off, 64);
            dpart.z += __shfl_xor(dpart.z, off, 64);
            dpart.w += __shfl_xor(dpart.w, off, 64);
        }
        const float den = esel + ((h == 0) ? dpart.x : (h == 1) ? dpart.y
                                 : (h == 2) ? dpart.z : dpart.w);

        float v = (acc0 + acc1) / den + b1;
        v = fmaf(v, scale, shift);
        v = fmaxf(v, 0.f);
        sh[wave][lane] = v;
        __threadfence_block();

        float gv = 0.f;
        if (lane < NCLASS) {
            #pragma unroll
            for (int k = 0; k < HC; ++k)
                gv = fmaf(sh[wave][k], sW[k * NCLASS + lane], gv);
            g[(size_t)node * NCLASS + lane] = gv;
        }
        float sv = gv * a2, dv = gv * d2;
        #pragma unroll
        for (int off = 32; off >= 1; off >>= 1) {
            sv += __shfl_xor(sv, off, 64);
            dv += __shfl_xor(dv, off, 64);
        }
        if (lane == 0) { as2o[node] = sv; ad2o[node] = dv; }
        __threadfence_block();
    }
}

// ---------------------------------------------------------------------------
// Kernel agg2: one wave per node, layer-2 aggregation (1 head) + final bias.
// Same prefetch-into-LDS structure, unroll 4.
// ---------------------------------------------------------------------------
__global__ __launch_bounds__(256) void k_agg2(
    const int* __restrict__ csr, const int* __restrict__ rowptr,
    const float* __restrict__ g, const float* __restrict__ as2,
    const float* __restrict__ ad2, const float* __restrict__ bias2,
    float* __restrict__ out, int n)
{
    __shared__ float sE[4][64];
    __shared__ int   sS[4][64];
    const int wave = threadIdx.x >> 6, lane = threadIdx.x & 63;
    const float b2 = (lane < NCLASS) ? bias2[lane] : 0.f;

    for (int node = blockIdx.x * 4 + wave; node < n; node += gridDim.x * 4) {
        const float ad2d = ad2[node];
        const float eself = __expf(leaky(as2[node] + ad2d));
        float acc0 = (lane < NCLASS) ? eself * g[(size_t)node * NCLASS + lane] : 0.f;
        float acc1 = 0.f;
        float dpart = 0.f;

        const int row = rowptr[node], end = rowptr[node + 1];
        for (int base = row; base < end; base += 64) {
            const int m = min(64, end - base);
            float e = 0.f;
            int eid = 0;
            if (lane < m) {
                eid = csr[base + lane];
                e = __expf(leaky(as2[eid] + ad2d));
            }
            dpart += e;
            sE[wave][lane] = e;
            sS[wave][lane] = eid;
            __threadfence_block();

            const float* eB = &sE[wave][0];
            const int*   sB = &sS[wave][0];
            int i = 0;
            if (lane < NCLASS) {
                for (; i + 4 <= m; i += 4) {
                    const int s0 = sB[i + 0], s1 = sB[i + 1];
                    const int s2 = sB[i + 2], s3 = sB[i + 3];
                    const float e0 = eB[i + 0], e1 = eB[i + 1];
                    const float e2 = eB[i + 2], e3 = eB[i + 3];
                    const float v0 = g[(size_t)s0 * NCLASS + lane];
                    const float v1 = g[(size_t)s1 * NCLASS + lane];
                    const float v2 = g[(size_t)s2 * NCLASS + lane];
                    const float v3 = g[(size_t)s3 * NCLASS + lane];
                    acc0 = fmaf(e0, v0, acc0);
                    acc1 = fmaf(e1, v1, acc1);
                    acc0 = fmaf(e2, v2, acc0);
                    acc1 = fmaf(e3, v3, acc1);
                }
                for (; i < m; ++i)
                    acc0 = fmaf(eB[i], g[(size_t)sB[i] * NCLASS + lane], acc0);
            }
            __threadfence_block();
        }

        #pragma unroll
        for (int off = 32; off >= 1; off >>= 1)
            dpart += __shfl_xor(dpart, off, 64);
        const float den = dpart + eself;

        if (lane < NCLASS)
            out[(size_t)node * NCLASS + lane] = (acc0 + acc1) / den + b2;
    }
}

extern "C" void kernel_launch(void* const* d_in, const int* in_sizes, int n_in,
                              void* d_out, int out_size, void* d_ws, size_t ws_size,
                              hipStream_t stream)
{
    const float* x    = (const float*)d_in[0];
    const int*   ei   = (const int*)  d_in[1];   // [2,E] int32
    const float* W1   = (const float*)d_in[2];
    const float* as1w = (const float*)d_in[3];
    const float* ad1w = (const float*)d_in[4];
    const float* b1   = (const float*)d_in[5];
    const float* gm   = (const float*)d_in[6];
    const float* bt   = (const float*)d_in[7];
    const float* mn   = (const float*)d_in[8];
    const float* vr   = (const float*)d_in[9];
    const float* W2   = (const float*)d_in[10];
    const float* as2w = (const float*)d_in[11];
    const float* ad2w = (const float*)d_in[12];
    const float* b2   = (const float*)d_in[13];

    const int n = in_sizes[0] / NFEAT;           // 100000
    const int E = in_sizes[1] / 2;               // 1600000
    const int* esrc = ei;
    const int* edst = ei + E;

    // workspace layout (4-byte units):
    // h1(64n) | as1(4n) | ad1(4n) | g(40n) | as2(n) | ad2(n) |
    // deg(n) cursor(n) [one memset] | rowptr(n+1) | bsum(ceil(n/1024)) | csr(E)
    float* ws   = (float*)d_ws;
    float* h1   = ws;
    float* a_s1 = h1   + (size_t)n * 64;
    float* a_d1 = a_s1 + (size_t)n * 4;
    float* gbuf = a_d1 + (size_t)n * 4;
    float* a_s2 = gbuf + (size_t)n * NCLASS;
    float* a_d2 = a_s2 + n;
    int*   deg    = (int*)(a_d2 + n);
    int*   cursor = deg + n;
    int*   rowptr = cursor + n;
    const int nb1 = (n + 1023) / 1024;
    int*   bsum   = rowptr + (n + 1);
    int*   csr    = bsum + nb1;
    float* outv = (float*)d_out;

    hipMemsetAsync(deg, 0, (size_t)n * 2 * sizeof(int), stream);  // deg + cursor

    const int eb = (E + 255) / 256;
    const int nblk = (n + 3) / 4;

    k_count<<<eb, 256, 0, stream>>>(edst, deg, E);
    k_scan1<<<nb1, 1024, 0, stream>>>(deg, rowptr, bsum, n);
    k_scan2<<<1, 128, 0, stream>>>(bsum, nb1);
    k_scan3<<<(n + 255) / 256, 256, 0, stream>>>(rowptr, bsum, n);
    k_fill <<<eb, 256, 0, stream>>>(esrc, edst, rowptr, cursor, csr, E);
    k_gemm1<<<2048, 256, 0, stream>>>(x, W1, as1w, ad1w, h1, a_s1, a_d1, n);
    k_agg1 <<<nblk, 256, 0, stream>>>(csr, rowptr, h1, a_s1, a_d1, b1, gm, bt, mn, vr,
                                      W2, as2w, ad2w, gbuf, a_s2, a_d2, n);
    k_agg2 <<<nblk, 256, 0, stream>>>(csr, rowptr, gbuf, a_s2, a_d2, b2, outv, n);
}